// Round 7
// baseline (367.673 us; speedup 1.0000x reference)
//
#include <hip/hip_runtime.h>
#include <hip/hip_bf16.h>
#include <hip/hip_fp16.h>

typedef int i32x4 __attribute__((ext_vector_type(4)));

// async global->LDS, 16B per lane; LDS dest = wave-uniform base + lane*16
#define GLL16(g, l) __builtin_amdgcn_global_load_lds( \
    (const __attribute__((address_space(1))) void*)(g), \
    (__attribute__((address_space(3))) void*)(l), 16, 0, 0)

#define CFENCE() asm volatile("" ::: "memory")

// ---------------- in-register H_16 butterfly helper ----------------
template<int NS>
__device__ __forceinline__ void hreg(float* v)
{
    #pragma unroll
    for (int h = 1; h < (1 << NS); h <<= 1)
        #pragma unroll
        for (int i = 0; i < 16; i++)
            if ((i & h) == 0) { float a = v[i], b = v[i + h]; v[i] = a + b; v[i + h] = a - b; }
}

// LDS element swizzle: logical float index e -> physical float index.
__device__ __forceinline__ int lswz(int e)
{
    const int r16 = e >> 4;
    return r16 * 16 + 4 * (((e >> 2) & 3) ^ ((r16 >> 1) & 3)) + (e & 3);
}

// ---------------- FWHT + per-token absmax int8 quant (device body) ----------------
template<int N, int TOKS>
__device__ __forceinline__ void fwht_quant_body(
    int bid,
    const float* __restrict__ in, long in_stride,
    char* __restrict__ outq, long out_stride,
    float* __restrict__ scales)
{
    constexpr int L = 256 / TOKS;          // threads per token
    static_assert(N == 16 * L, "N must be 16*threads-per-token");
    __shared__ float sx[TOKS * N];
    __shared__ float red[4];

    const int tid = threadIdx.x;
    const int tk  = tid / L;
    const int lt  = tid % L;
    const long tok = (long)bid * TOKS + tk;
    const float* row = in + tok * in_stride;
    float* s = sx + tk * N;

    float v[16];
    {
        const float4* r4 = (const float4*)(row + (size_t)lt * 16);
        float4 a[4];
        #pragma unroll
        for (int i = 0; i < 4; i++) a[i] = r4[i];
        #pragma unroll
        for (int i = 0; i < 4; i++) {
            v[4*i] = a[i].x; v[4*i+1] = a[i].y; v[4*i+2] = a[i].z; v[4*i+3] = a[i].w;
        }
    }
    hreg<4>(v);                            // h = 1,2,4,8
    {
        const int psw = (lt >> 1) & 3;
        #pragma unroll
        for (int i = 0; i < 4; i++)
            *(float4*)(s + lt * 16 + 4 * (i ^ psw)) =
                make_float4(v[4*i], v[4*i+1], v[4*i+2], v[4*i+3]);
    }
    __syncthreads();

    const int o = lt & 15, ss = lt >> 4;
    #pragma unroll
    for (int j = 0; j < 16; j++) v[j] = s[lswz(o + 256 * ss + 16 * j)];
    hreg<(L == 256) ? 4 : 3>(v);           // h = 16..128 (L=256) or 16..64 (L=128)
    #pragma unroll
    for (int j = 0; j < 16; j++) s[lswz(o + 256 * ss + 16 * j)] = v[j];
    __syncthreads();

    #pragma unroll
    for (int j = 0; j < 16; j++) v[j] = s[lswz(o + 16 * ss + L * j)];
    hreg<4>(v);                            // top 4 stages

    const float rn = 1.0f / sqrtf((float)N);
    float m = 0.0f;
    #pragma unroll
    for (int j = 0; j < 16; j++) { v[j] *= rn; m = fmaxf(m, fabsf(v[j])); }
    for (int off = 32; off > 0; off >>= 1) m = fmaxf(m, __shfl_down(m, off, 64));
    if ((tid & 63) == 0) red[tid >> 6] = m;
    __syncthreads();
    float mm;
    if (TOKS == 1) mm = fmaxf(fmaxf(red[0], red[1]), fmaxf(red[2], red[3]));
    else           mm = fmaxf(red[2 * tk], red[2 * tk + 1]);
    mm = fmaxf(mm, 1e-5f);
    const float sc = 127.0f / mm;
    if (lt == 0) scales[tok] = sc;
    __syncthreads();                       // sx about to be reused as i8 buffer

    char* ct = (char*)sx + tk * N;
    #pragma unroll
    for (int j = 0; j < 16; j++) {
        float q = fminf(fmaxf(rintf(v[j] * sc), -127.0f), 127.0f);
        ct[o + 16 * ss + L * j] = (char)q;
    }
    __syncthreads();
    int4* dst = (int4*)(outq + tok * out_stride);
    dst[lt] = ((const int4*)ct)[lt];
}

// ---------------- abs-sum device body (per-tensor mean|w| numerator) ---------------
__device__ __forceinline__ void abs_sum_body(int bid, int nb,
                                             const float* __restrict__ w0,
                                             const float* __restrict__ w1, int n4,
                                             double* __restrict__ out)
{
    const int sel = bid & 1;
    const float4* w4 = (const float4*)(sel ? w1 : w0);
    const int b = bid >> 1, nbb = nb >> 1;
    double acc = 0.0;
    for (int i = b * blockDim.x + threadIdx.x; i < n4; i += nbb * blockDim.x) {
        float4 v = w4[i];
        acc += (double)fabsf(v.x) + (double)fabsf(v.y) + (double)fabsf(v.z) + (double)fabsf(v.w);
    }
    for (int o = 32; o > 0; o >>= 1) acc += __shfl_down(acc, o, 64);
    __shared__ double part[4];
    int lane = threadIdx.x & 63, wv = threadIdx.x >> 6;
    if (lane == 0) part[wv] = acc;
    __syncthreads();
    if (threadIdx.x == 0) atomicAdd(&out[sel], part[0] + part[1] + part[2] + part[3]);
}

// ---------------- fused: fwht1 (blocks 0..nfw-1)  ||  abs-sum (rest) ----------------
__global__ __launch_bounds__(256) void fused_fwht_abs_kernel(
    const float* __restrict__ X, char* __restrict__ xq1, float* __restrict__ sx1,
    const float* __restrict__ w0, const float* __restrict__ w1, int n4,
    double* __restrict__ sums, int nfw, int nabs)
{
    if ((int)blockIdx.x < nfw)
        fwht_quant_body<2048, 2>(blockIdx.x, X, 2048, xq1, 2048, sx1);
    else
        abs_sum_body(blockIdx.x - nfw, nabs, w0, w1, n4, sums);
}

// ---------------- ternary weight quant -> MFMA-fragment-packed i8 ----------------
// Packed layout: chunk c = ((o>>4)*(K>>6) + (k>>6))*64 + ((o&15) | (((k>>4)&3)<<4));
// byte (k&15) within chunk. Chunk c holds exactly what MFMA lane (o&15)|(kslot<<4)
// needs for the 16x16x64 B-fragment of tile (o>>4, k>>6) -> a wave's b-frag load is
// one coalesced 1 KB global_load_dwordx4, no LDS staging needed in the GEMM.
// Thresholding: clip(rint(v/s),-1,1) == (|v| > 0.5*s) ? sign(v) : 0 (half-even).
__global__ __launch_bounds__(256) void wquant_pack_kernel(
    const float* __restrict__ w0, const float* __restrict__ w1,
    const double* __restrict__ sums, double inv_count,
    char* __restrict__ o0, char* __restrict__ o1)
{
    const int sel = blockIdx.x & 1;
    const float* wp = sel ? w1 : w0;
    char* op = sel ? o1 : o0;
    const int K = sel ? 4096 : 2048;
    const int kshift = sel ? 6 : 5;        // log2(K/64)
    float s = (float)(sums[sel] * inv_count);
    s = fmaxf(s, 1e-5f);
    const float t0 = 0.5f * s;

    const int c = (int)(blockIdx.x >> 1) * 256 + threadIdx.x;   // chunk index
    const int lane = c & 63;
    const int g = c >> 6;
    const int kt = g & ((1 << kshift) - 1);
    const int ot = g >> kshift;
    const int o = ot * 16 + (lane & 15);
    const int k0 = (kt << 6) + ((lane >> 4) << 4);

    const float4* r4 = (const float4*)(wp + (size_t)o * K + k0);
    float4 a[4];
    #pragma unroll
    for (int i = 0; i < 4; i++) a[i] = r4[i];

    union { char ch[16]; int4 v; } u;
    const float* f = (const float*)a;
    #pragma unroll
    for (int i = 0; i < 16; i++)
        u.ch[i] = (fabsf(f[i]) > t0) ? (f[i] > 0.0f ? 1 : -1) : 0;
    *(int4*)(op + (size_t)c * 16) = u.v;
}

// ---------------- FWHT + quant, f16 input (N=4096, 1 token/block) ----------------
__global__ __launch_bounds__(256) void fwht_quant_f16_kernel(
    const __half* __restrict__ in, long in_stride,
    char* __restrict__ outq, long out_stride,
    float* __restrict__ scales)
{
    constexpr int N = 4096, L = 256;
    __shared__ float sx[N];
    __shared__ float red[4];

    const int lt = threadIdx.x;
    const long tok = blockIdx.x;
    const __half* row = in + tok * in_stride;
    float* s = sx;

    float v[16];
    {
        const int4* r4 = (const int4*)row;
        int4 q0 = r4[2 * lt], q1 = r4[2 * lt + 1];
        const __half2* h0 = (const __half2*)&q0;
        const __half2* h1 = (const __half2*)&q1;
        #pragma unroll
        for (int i = 0; i < 4; i++) {
            float2 f = __half22float2(h0[i]);
            v[2*i] = f.x; v[2*i+1] = f.y;
        }
        #pragma unroll
        for (int i = 0; i < 4; i++) {
            float2 f = __half22float2(h1[i]);
            v[8+2*i] = f.x; v[8+2*i+1] = f.y;
        }
    }
    hreg<4>(v);                            // h = 1,2,4,8
    {
        const int psw = (lt >> 1) & 3;
        #pragma unroll
        for (int i = 0; i < 4; i++)
            *(float4*)(s + lt * 16 + 4 * (i ^ psw)) =
                make_float4(v[4*i], v[4*i+1], v[4*i+2], v[4*i+3]);
    }
    __syncthreads();

    const int o = lt & 15, ss = lt >> 4;
    #pragma unroll
    for (int j = 0; j < 16; j++) v[j] = s[lswz(o + 256 * ss + 16 * j)];
    hreg<4>(v);                            // h = 16..128
    #pragma unroll
    for (int j = 0; j < 16; j++) s[lswz(o + 256 * ss + 16 * j)] = v[j];
    __syncthreads();

    #pragma unroll
    for (int j = 0; j < 16; j++) v[j] = s[lswz(o + 16 * ss + L * j)];
    hreg<4>(v);                            // h = 256..2048

    const float rn = 1.0f / sqrtf((float)N);
    float m = 0.0f;
    #pragma unroll
    for (int j = 0; j < 16; j++) { v[j] *= rn; m = fmaxf(m, fabsf(v[j])); }
    for (int off = 32; off > 0; off >>= 1) m = fmaxf(m, __shfl_down(m, off, 64));
    if ((lt & 63) == 0) red[lt >> 6] = m;
    __syncthreads();
    float mm = fmaxf(fmaxf(red[0], red[1]), fmaxf(red[2], red[3]));
    mm = fmaxf(mm, 1e-5f);
    const float sc = 127.0f / mm;
    if (lt == 0) scales[tok] = sc;
    __syncthreads();                       // sx about to be reused as i8 buffer

    char* ct = (char*)sx;
    #pragma unroll
    for (int j = 0; j < 16; j++) {
        float q = fminf(fmaxf(rintf(v[j] * sc), -127.0f), 127.0f);
        ct[o + 16 * ss + L * j] = (char)q;
    }
    __syncthreads();
    int4* dst = (int4*)(outq + tok * out_stride);
    dst[lt] = ((const int4*)ct)[lt];
}

// ---------------- i8 MFMA GEMM: A via LDS, B direct from packed global ----------
// 128x128 tile, 4 waves, 64x64/wave. A staged in a 2-deep LDS ring (16 KB total);
// B-fragments load straight from the packed weight layout (1 KB coalesced per
// wave-frag) -- L2/L3-resident (per-K-step slice = N*64 <= 256 KB). B is
// reg-double-buffered across K-tiles: counted vmcnt(4) keeps the next tile's 4
// B-loads in flight across each barrier; only A's 2 GLLs are drained.
// LDS pipe per block-tile drops ~576 -> ~288 cyc, below the 326-cyc MFMA floor.
#define BM 128
#define BN 128
#define BK 64

__global__ __launch_bounds__(256, 3) void gemm_bt_kernel(
    const char* __restrict__ A, int lda,
    const char* __restrict__ Bp,            // fragment-packed ternary weights
    void* __restrict__ Cv, int ldc,
    int K, int lognx,
    const float* __restrict__ sx,
    const double* __restrict__ wsum, double inv_count,
    int do_relu2, int out_f16)
{
    __shared__ __align__(16) char As[2][BM * BK];   // 2 x 8 KB

    // XCD row-band swizzle (grid % 8 == 0 -> bijective)
    const int bid = blockIdx.x;
    const int xcd = bid & 7;
    const int n = bid >> 3;
    const int nper = gridDim.x >> 3;
    const int bx = n & ((1 << lognx) - 1);
    const int by = xcd * (nper >> lognx) + (n >> lognx);
    const int row0 = by * BM;
    const int col0 = bx * BN;

    const int tid = threadIdx.x;
    const int lane = tid & 63;
    const int w = tid >> 6;          // 4 waves
    const int wr = w >> 1;           // 0..1 : 64-row band
    const int wc = w & 1;            // 0..1 : 64-col band

    i32x4 acc[4][4] = {};            // 64 AGPR

    // ---- A staging: linear LDS dest, swizzled global source ----
    const int srow = w * 16 + (lane >> 2);                    // 0..63
    const int sseg = ((lane & 3) ^ ((lane >> 3) & 3)) << 4;
    const char* Ag0 = A + (size_t)(row0 + srow) * lda + sseg;
    const char* Ag1 = Ag0 + (size_t)64 * lda;
    const int wdst = w * 1024;

    // ---- A fragment read addressing (swizzled) ----
    const int fr = lane & 15;
    const int fks = lane >> 4;
    const int rsw = ((fks ^ ((fr >> 1) & 3)) << 4);
    const int aoff = (wr * 64 + fr) * BK + rsw;    // + i*1024

    // ---- B packed addressing: frag j, tile t at Bb + j*jstep + t*1024 ----
    const int NKT = K >> 6;
    const size_t jstep = (size_t)NKT << 10;
    const char* Bb = Bp + (((size_t)((col0 >> 4) + wc * 4) * NKT) << 10) + (lane << 4);

    const int NT = K >> 6;           // 32 (GEMM1) / 64 (GEMM2)

    auto stage = [&](int tt) {
        const int sb = tt & 1;
        const int ko = tt * BK;
        GLL16(Ag0 + ko, &As[sb][wdst]);
        GLL16(Ag1 + ko, &As[sb][wdst + 4096]);
    };
    auto bload = [&](i32x4* bq, int tt) __attribute__((always_inline)) {
        const size_t to = (size_t)tt << 10;
        #pragma unroll
        for (int j = 0; j < 4; ++j) bq[j] = *(const i32x4*)(Bb + j * jstep + to);
    };
    auto compute = [&](int t, const i32x4* bq) __attribute__((always_inline)) {
        const char* as = As[t & 1];
        i32x4 af[4];
        #pragma unroll
        for (int i = 0; i < 4; ++i) af[i] = *(const i32x4*)(as + aoff + i * 1024);
        __builtin_amdgcn_s_setprio(1);
        #pragma unroll
        for (int i = 0; i < 4; ++i)
            #pragma unroll
            for (int j = 0; j < 4; ++j)
                acc[i][j] = __builtin_amdgcn_mfma_i32_16x16x64_i8(af[i], bq[j], acc[i][j], 0, 0, 0);
        __builtin_amdgcn_s_setprio(0);
    };

    i32x4 bqA[4], bqB[4];

    // prologue: A tile 0 + B tile 0
    stage(0);
    bload(bqA, 0);
    asm volatile("s_waitcnt vmcnt(0)" ::: "memory");
    __builtin_amdgcn_s_barrier();
    CFENCE();

    int t = 0;
    for (; t < NT - 2; t += 2) {
        stage(t + 1);                // 2 GLL (oldest)
        bload(bqB, t + 1);           // 4 B-loads stay in flight across barrier
        compute(t, bqA);
        asm volatile("s_waitcnt vmcnt(4)" ::: "memory");   // A(t+1) landed
        __builtin_amdgcn_s_barrier();
        CFENCE();
        stage(t + 2);
        bload(bqA, t + 2);
        compute(t + 1, bqB);         // compiler waits the counted vmcnt for bqB
        asm volatile("s_waitcnt vmcnt(4)" ::: "memory");   // A(t+2) landed
        __builtin_amdgcn_s_barrier();
        CFENCE();
    }
    // tail: t == NT-2; bqA holds tile NT-2
    stage(NT - 1);
    bload(bqB, NT - 1);
    compute(NT - 2, bqA);
    asm volatile("s_waitcnt vmcnt(4)" ::: "memory");       // A(NT-1) landed
    __builtin_amdgcn_s_barrier();
    CFENCE();
    compute(NT - 1, bqB);

    // epilogue: out = (float)acc * s_w / scale_x[row]; optional relu^2; f32 or f16
    float sw = (float)(wsum[0] * inv_count);
    sw = fmaxf(sw, 1e-5f);
    const int qd = lane >> 4;
    if (out_f16) {
        __half* C = (__half*)Cv;
        #pragma unroll
        for (int i = 0; i < 4; ++i) {
            #pragma unroll
            for (int r = 0; r < 4; ++r) {
                int rowm = row0 + wr * 64 + i * 16 + qd * 4 + r;
                float esc = sw / sx[rowm];
                __half* crow = C + (size_t)rowm * ldc + col0 + wc * 64;
                #pragma unroll
                for (int j = 0; j < 4; ++j) {
                    float v = (float)acc[i][j][r] * esc;
                    if (do_relu2) { v = fmaxf(v, 0.0f); v = v * v; }
                    crow[j * 16 + fr] = __float2half(v);
                }
            }
        }
    } else {
        float* C = (float*)Cv;
        #pragma unroll
        for (int i = 0; i < 4; ++i) {
            #pragma unroll
            for (int r = 0; r < 4; ++r) {
                int rowm = row0 + wr * 64 + i * 16 + qd * 4 + r;
                float esc = sw / sx[rowm];
                float* crow = C + (size_t)rowm * ldc + col0 + wc * 64;
                #pragma unroll
                for (int j = 0; j < 4; ++j) {
                    float v = (float)acc[i][j][r] * esc;
                    if (do_relu2) { v = fmaxf(v, 0.0f); v = v * v; }
                    crow[j * 16 + fr] = v;
                }
            }
        }
    }
}

extern "C" void kernel_launch(void* const* d_in, const int* in_sizes, int n_in,
                              void* d_out, int out_size, void* d_ws, size_t ws_size,
                              hipStream_t stream)
{
    const float* X   = (const float*)d_in[0];   // (4,2048,2048) f32
    const float* Wup = (const float*)d_in[1];   // (4096,2048)   f32
    const float* Wdn = (const float*)d_in[2];   // (2048,4096)   f32
    float* out = (float*)d_out;                 // (4,2048,2048) f32

    const int Mtok = 8192, H = 2048, I = 4096;
    const int NW = H * I;                       // 8388608 = 2^23 weights per tensor

    // workspace layout
    char* ws = (char*)d_ws;
    double* sums = (double*)ws;                                  // 2 doubles
    float* sx1 = (float*)(ws + 1024);                            // 8192 f32
    float* sx2 = (float*)(ws + 1024 + 32768);                    // 8192 f32
    char* wqup = ws + (1 << 20);                                 // 8.4 MB packed i8
    char* wqdn = wqup + (size_t)NW;                              // 8.4 MB packed i8
    char* xq1  = wqdn + (size_t)NW;                              // 16.8 MB (i8)
    char* hbuf = xq1 + (size_t)Mtok * H;                         // 67 MB (h f16; xq2 i8 overlaid per-row)

    hipMemsetAsync(sums, 0, 16, stream);
    // fused: fwht1 (4096 blocks) || abs-sum both tensors (1024 blocks)
    fused_fwht_abs_kernel<<<4096 + 1024, 256, 0, stream>>>(
        X, xq1, sx1, Wup, Wdn, NW / 4, sums, 4096, 1024);
    const double invc = 1.0 / (double)NW;       // exactly 2^-23
    // packed ternary quant: NW/16 chunks per tensor, 2048 blocks each, interleaved
    wquant_pack_kernel<<<4096, 256, 0, stream>>>(Wup, Wdn, sums, invc, wqup, wqdn);

    // GEMM1 + relu^2 fused -> hbuf (f16, ld=I); grid 32x64 tiles -> 1-D swizzled, lognx=5
    gemm_bt_kernel<<<(I / BN) * (Mtok / BM), 256, 0, stream>>>(
        xq1, H, wqup, hbuf, I, H, 5, sx1, &sums[0], invc, 1, 1);
    // stage 2: FWHT(I=4096) from f16 + quant; xq2 (i8) overlaid on hbuf rows (stride 2*I bytes)
    fwht_quant_f16_kernel<<<Mtok, 256, 0, stream>>>((const __half*)hbuf, I, hbuf, 2 * I, sx2);
    // GEMM2 -> out (f32); grid 16x64 tiles -> 1-D swizzled, lognx=4
    gemm_bt_kernel<<<(H / BN) * (Mtok / BM), 256, 0, stream>>>(
        (const char*)hbuf, 2 * I, wqdn, out, H, I, 4, sx2, &sums[1], invc, 0, 0);
}